// Round 17
// baseline (504.501 us; speedup 1.0000x reference)
//
#include <hip/hip_runtime.h>
#include <hip/hip_bf16.h>
#include <stdint.h>

#define B_DIM 16384
#define D_DIM 512
// Embeddings quantized as int8 q = rne(127*x): dot scales by 127^2.
#define ILOGIT_SCALE (1.0f / (127.0f * 127.0f * 0.07f))
#define ILOGIT_SCALE_L2 (ILOGIT_SCALE * 1.44269504088896340736f)

typedef int i32x4 __attribute__((ext_vector_type(4)));
typedef float f32x4 __attribute__((ext_vector_type(4)));

typedef const __attribute__((address_space(1))) void* gptr_t;
typedef __attribute__((address_space(3))) void* lptr_t;

// Fragment-linear i8 layout, 64-ROW chunks (identical for Pn and Tn):
//   chunk(RB = row>>6, KT = k>>6) = (RB*8 + KT)*4096 bytes   (64 rows x 64 k)
//   subtile mq = (row>>4)&3 -> 1 KB at mq*1024
//   slot lane = ((k>>4)&3)*16 + (row&15) -> 16 B at lane*16
//   byte = k&15
// => one i8 MFMA fragment = ONE contiguous 1-KB lane-linear read (zero bank
//    conflicts from LDS), and any (64-row, 4-K-tile) half-chunk = one
//    contiguous 16-KB span (pure linear gload_lds staging).

// One wave per row: load 512 fp32, L2-normalize, quantize q=rne(127x),
// write one 8-B fragment slot per lane. (r12-proven.)
__global__ __launch_bounds__(256) void normalize_kernel(const float* __restrict__ in,
                                                        uint8_t* __restrict__ out) {
  int wid = threadIdx.x >> 6;
  int lane = threadIdx.x & 63;
  int row = blockIdx.x * 4 + wid;
  const float* r = in + (size_t)row * D_DIM;
  float4 v0 = ((const float4*)r)[lane * 2];
  float4 v1 = ((const float4*)r)[lane * 2 + 1];
  float ssq = v0.x * v0.x + v0.y * v0.y + v0.z * v0.z + v0.w * v0.w +
              v1.x * v1.x + v1.y * v1.y + v1.z * v1.z + v1.w * v1.w;
#pragma unroll
  for (int m = 1; m < 64; m <<= 1) ssq += __shfl_xor(ssq, m);
  float s = 127.0f / fmaxf(sqrtf(ssq), 1e-12f);
  int q0 = __float2int_rn(v0.x * s), q1 = __float2int_rn(v0.y * s);
  int q2 = __float2int_rn(v0.z * s), q3 = __float2int_rn(v0.w * s);
  int q4 = __float2int_rn(v1.x * s), q5 = __float2int_rn(v1.y * s);
  int q6 = __float2int_rn(v1.z * s), q7 = __float2int_rn(v1.w * s);
  uint2 o;
  o.x = (uint32_t)(q0 & 255) | ((uint32_t)(q1 & 255) << 8) |
        ((uint32_t)(q2 & 255) << 16) | ((uint32_t)q3 << 24);
  o.y = (uint32_t)(q4 & 255) | ((uint32_t)(q5 & 255) << 8) |
        ((uint32_t)(q6 & 255) << 16) | ((uint32_t)q7 << 24);
  size_t addr = ((size_t)(row >> 6) * 8 + (lane >> 3)) * 4096 +
                (size_t)((row >> 4) & 3) * 1024 +
                (size_t)((((lane >> 1) & 3) << 4) | (row & 15)) * 16 +
                (lane & 1) * 8;
  *(uint2*)(out + addr) = o;
}

// i8 128x128-tile NT GEMM, DUAL-panel LDS: both A (64 KB) and B (64 KB)
// panels resident -> ZERO per-K-tile global loads, all fragment reads on
// the LDS pipe (lane-linear, conflict-free). Barrier-free K-loop; fill
// split in two K-halves so half the fill hides under compute. 8 waves
// (2Mx4N, wave 64x32). mfma_i32_16x16x64_i8 exact. Fused epilogue.
__global__ __launch_bounds__(512, 2) void infonce_main(const uint8_t* __restrict__ P,
                                                       const uint8_t* __restrict__ T,
                                                       float* __restrict__ row_sum,
                                                       float* __restrict__ col_sum,
                                                       float* __restrict__ diag) {
  __shared__ __align__(16) uint8_t Asm[65536];  // rows brow..+127, all K
  __shared__ __align__(16) uint8_t Bsm[65536];  // cols bcol..+127, all K

  // XCD raster: xcd owns 16 brow strips (2048 rows = 1 MB i8, L2-resident);
  // within XCD, brow fastest -> concurrent blocks share the bcol B-tile.
  int bid = blockIdx.x;          // 0..16383
  int xcd = bid & 7;
  int q = bid >> 3;              // 0..2047
  int brow = (xcd * 16 + (q & 15)) << 7;
  int bcol = (q >> 4) << 7;

  int tid = threadIdx.x;
  int lane = tid & 63;
  int wid = tid >> 6;            // 0..7
  int mw = wid >> 2;             // M-wave (2): rows mw*64..+63
  int nw = wid & 3;              // N-wave (4): cols nw*32..+31
  int rlane = lane >> 4;
  int clane = lane & 15;

  size_t Ag = (size_t)(brow >> 6) * 32768;  // A panel = global [Ag, Ag+64K)
  size_t Bg = (size_t)(bcol >> 6) * 32768;

  // Stage one 16-KB span (rbl chunk, K-half ph): 2 gload_lds(16B)/thread.
#define SPAN(ARR, SRC, GBASE, RBL, PH)                                         \
  do {                                                                         \
    size_t go_ = (GBASE) + (size_t)(RBL)*32768 + (size_t)(PH)*16384;           \
    uint32_t lo_ = (RBL)*32768u + (PH)*16384u;                                 \
    _Pragma("unroll") for (int it = 0; it < 2; ++it) {                         \
      int s_ = it * 512 + tid;                                                 \
      __builtin_amdgcn_global_load_lds((gptr_t)(SRC + go_ + (size_t)s_ * 16),  \
                                       (lptr_t)(&ARR[lo_] + s_ * 16), 16, 0, 0);\
    }                                                                          \
  } while (0)

  // Phase 1: K-tiles 0-3 of both panels (64 KB).
  SPAN(Asm, P, Ag, 0, 0);
  SPAN(Asm, P, Ag, 1, 0);
  SPAN(Bsm, T, Bg, 0, 0);
  SPAN(Bsm, T, Bg, 1, 0);
  __syncthreads();  // K-half 1 resident
  // Phase 2 issued now: streams in while we compute t=0..3.
  SPAN(Asm, P, Ag, 0, 1);
  SPAN(Asm, P, Ag, 1, 1);
  SPAN(Bsm, T, Bg, 0, 1);
  SPAN(Bsm, T, Bg, 1, 1);
#undef SPAN

  // Fragment addresses (lane-linear 1-KB reads):
  //   A(t,m): Asm[mw*32768 + t*4096 + m*1024 + lane*16]
  //   B(t,n): Bsm[(nw>>1)*32768 + t*4096 + ((nw&1)*2+n)*1024 + lane*16]
  const uint8_t* lA = &Asm[(size_t)mw * 32768 + (size_t)lane * 16];
  const uint8_t* lB = &Bsm[(size_t)(nw >> 1) * 32768 + (size_t)((nw & 1) * 2) * 1024 +
                           (size_t)lane * 16];

  i32x4 acc[4][2] = {};
  i32x4 a[4], b[2];

#define RD(t)                                                                  \
  do {                                                                         \
    _Pragma("unroll") for (int m = 0; m < 4; ++m)                              \
        a[m] = *(const i32x4*)(lA + (t)*4096 + m * 1024);                      \
    _Pragma("unroll") for (int n = 0; n < 2; ++n)                              \
        b[n] = *(const i32x4*)(lB + (t)*4096 + n * 1024);                      \
  } while (0)
#define MM()                                                                   \
  _Pragma("unroll") for (int m = 0; m < 4; ++m)                                \
      _Pragma("unroll") for (int n = 0; n < 2; ++n)                            \
          acc[m][n] = __builtin_amdgcn_mfma_i32_16x16x64_i8(a[m], b[n], acc[m][n], 0, 0, 0)

  RD(0);
#pragma unroll
  for (int t = 0; t < 4; ++t) {
    i32x4 an[4], bn[2];
    if (t < 3) {
#pragma unroll
      for (int m = 0; m < 4; ++m) an[m] = *(const i32x4*)(lA + (t + 1) * 4096 + m * 1024);
#pragma unroll
      for (int n = 0; n < 2; ++n) bn[n] = *(const i32x4*)(lB + (t + 1) * 4096 + n * 1024);
    }
    MM();
    if (t < 3) {
#pragma unroll
      for (int m = 0; m < 4; ++m) a[m] = an[m];
#pragma unroll
      for (int n = 0; n < 2; ++n) b[n] = bn[n];
    }
  }
  asm volatile("s_waitcnt vmcnt(0)" ::: "memory");
  __syncthreads();  // K-half 2 resident
  RD(4);
#pragma unroll
  for (int t = 4; t < 8; ++t) {
    i32x4 an[4], bn[2];
    if (t < 7) {
#pragma unroll
      for (int m = 0; m < 4; ++m) an[m] = *(const i32x4*)(lA + (t + 1) * 4096 + m * 1024);
#pragma unroll
      for (int n = 0; n < 2; ++n) bn[n] = *(const i32x4*)(lB + (t + 1) * 4096 + n * 1024);
    }
    MM();
    if (t < 7) {
#pragma unroll
      for (int m = 0; m < 4; ++m) a[m] = an[m];
#pragma unroll
      for (int n = 0; n < 2; ++n) b[n] = bn[n];
    }
  }
#undef RD
#undef MM

  // Epilogue: ex = 2^(acc * S*log2e); diag only in its branch.
  f32x4 ex[4][2];
#pragma unroll
  for (int m = 0; m < 4; ++m)
#pragma unroll
    for (int n = 0; n < 2; ++n)
#pragma unroll
      for (int j = 0; j < 4; ++j) {
        float ai = (float)acc[m][n][j];
        int grow = brow + mw * 64 + m * 16 + rlane * 4 + j;
        int gcol = bcol + nw * 32 + n * 16 + clane;
        if (grow == gcol) diag[grow] = ai * ILOGIT_SCALE;
        ex[m][n][j] = exp2f(ai * ILOGIT_SCALE_L2);
      }

  // Row sums (wave covers 32 cols): n-pair + 16-lane column group reduce.
#pragma unroll
  for (int m = 0; m < 4; ++m)
#pragma unroll
    for (int j = 0; j < 4; ++j) {
      float rs = ex[m][0][j] + ex[m][1][j];
      rs += __shfl_xor(rs, 1);
      rs += __shfl_xor(rs, 2);
      rs += __shfl_xor(rs, 4);
      rs += __shfl_xor(rs, 8);
      if (clane == 0)
        atomicAdd(&row_sum[brow + mw * 64 + m * 16 + rlane * 4 + j], rs);
    }

  // Col sums (wave covers 64 rows): m/reg reduce + 4 row-group shfl.
#pragma unroll
  for (int n = 0; n < 2; ++n) {
    float cs = 0.f;
#pragma unroll
    for (int m = 0; m < 4; ++m)
#pragma unroll
      for (int j = 0; j < 4; ++j) cs += ex[m][n][j];
    cs += __shfl_xor(cs, 16);
    cs += __shfl_xor(cs, 32);
    if (rlane == 0) atomicAdd(&col_sum[bcol + nw * 32 + n * 16 + clane], cs);
  }
}

__global__ __launch_bounds__(256) void finalize_kernel(const float* __restrict__ rs,
                                                       const float* __restrict__ cs,
                                                       const float* __restrict__ dg,
                                                       float* __restrict__ out) {
  float s = 0.f;
  for (int i = threadIdx.x; i < B_DIM; i += 256)
    s += 0.5f * (logf(rs[i]) + logf(cs[i])) - dg[i];
#pragma unroll
  for (int m = 1; m < 64; m <<= 1) s += __shfl_xor(s, m);
  __shared__ float red[4];
  if ((threadIdx.x & 63) == 0) red[threadIdx.x >> 6] = s;
  __syncthreads();
  if (threadIdx.x == 0)
    out[0] = (red[0] + red[1] + red[2] + red[3]) * (1.0f / (float)B_DIM);
}

extern "C" void kernel_launch(void* const* d_in, const int* in_sizes, int n_in,
                              void* d_out, int out_size, void* d_ws, size_t ws_size,
                              hipStream_t stream) {
  const float* p = (const float*)d_in[0];
  const float* t = (const float*)d_in[1];
  float* out = (float*)d_out;

  char* ws = (char*)d_ws;
  const size_t embBytes = (size_t)B_DIM * D_DIM;  // 8 MB i8
  uint8_t* Pn = (uint8_t*)ws;
  uint8_t* Tn = (uint8_t*)(ws + embBytes);
  float* row_sum = (float*)(ws + 2 * embBytes);
  float* col_sum = row_sum + B_DIM;
  float* diag = col_sum + B_DIM;

  hipMemsetAsync(row_sum, 0, 2 * (size_t)B_DIM * sizeof(float), stream);
  normalize_kernel<<<B_DIM / 4, 256, 0, stream>>>(p, Pn);
  normalize_kernel<<<B_DIM / 4, 256, 0, stream>>>(t, Tn);
  infonce_main<<<(B_DIM / 128) * (B_DIM / 128), 512, 0, stream>>>(Pn, Tn, row_sum, col_sum, diag);
  finalize_kernel<<<1, 256, 0, stream>>>(row_sum, col_sum, diag, out);
}

// Round 18
// 244.734 us; speedup vs baseline: 2.0614x; 2.0614x over previous
//
#include <hip/hip_runtime.h>
#include <hip/hip_bf16.h>
#include <stdint.h>

#define B_DIM 16384
#define D_DIM 512
// Embeddings quantized as int8 q = rne(127*x): dot scales by 127^2.
#define ILOGIT_SCALE (1.0f / (127.0f * 127.0f * 0.07f))
#define ILOGIT_SCALE_L2 (ILOGIT_SCALE * 1.44269504088896340736f)

typedef int i32x4 __attribute__((ext_vector_type(4)));
typedef float f32x4 __attribute__((ext_vector_type(4)));

typedef const __attribute__((address_space(1))) void* gptr_t;
typedef __attribute__((address_space(3))) void* lptr_t;

// Fragment-linear i8 layout, 64-ROW chunks (identical for Pn and Tn):
//   chunk(RB = row>>6, KT = k>>6) = (RB*8 + KT)*4096 bytes   (64 rows x 64 k)
//   subtile mq = (row>>4)&3 -> 1 KB at mq*1024
//   slot lane = ((k>>4)&3)*16 + (row&15) -> 16 B at lane*16
//   byte = k&15
// => one i8 MFMA fragment = ONE contiguous 1-KB lane-linear read, and a
//    64-row panel (all K) = ONE contiguous 32-KB span.

// One wave per row: load 512 fp32, L2-normalize, quantize q=rne(127x),
// write one 8-B fragment slot per lane. (r12-proven.)
__global__ __launch_bounds__(256) void normalize_kernel(const float* __restrict__ in,
                                                        uint8_t* __restrict__ out) {
  int wid = threadIdx.x >> 6;
  int lane = threadIdx.x & 63;
  int row = blockIdx.x * 4 + wid;
  const float* r = in + (size_t)row * D_DIM;
  float4 v0 = ((const float4*)r)[lane * 2];
  float4 v1 = ((const float4*)r)[lane * 2 + 1];
  float ssq = v0.x * v0.x + v0.y * v0.y + v0.z * v0.z + v0.w * v0.w +
              v1.x * v1.x + v1.y * v1.y + v1.z * v1.z + v1.w * v1.w;
#pragma unroll
  for (int m = 1; m < 64; m <<= 1) ssq += __shfl_xor(ssq, m);
  float s = 127.0f / fmaxf(sqrtf(ssq), 1e-12f);
  int q0 = __float2int_rn(v0.x * s), q1 = __float2int_rn(v0.y * s);
  int q2 = __float2int_rn(v0.z * s), q3 = __float2int_rn(v0.w * s);
  int q4 = __float2int_rn(v1.x * s), q5 = __float2int_rn(v1.y * s);
  int q6 = __float2int_rn(v1.z * s), q7 = __float2int_rn(v1.w * s);
  uint2 o;
  o.x = (uint32_t)(q0 & 255) | ((uint32_t)(q1 & 255) << 8) |
        ((uint32_t)(q2 & 255) << 16) | ((uint32_t)q3 << 24);
  o.y = (uint32_t)(q4 & 255) | ((uint32_t)(q5 & 255) << 8) |
        ((uint32_t)(q6 & 255) << 16) | ((uint32_t)q7 << 24);
  size_t addr = ((size_t)(row >> 6) * 8 + (lane >> 3)) * 4096 +
                (size_t)((row >> 4) & 3) * 1024 +
                (size_t)((((lane >> 1) & 3) << 4) | (row & 15)) * 16 +
                (lane & 1) * 8;
  *(uint2*)(out + addr) = o;
}

// i8 64x256-tile NT GEMM (r14 champion structure + depth-2 B prefetch):
// 4 waves share a 64-row A-panel in 32 KB LDS (one barrier); each wave owns
// a 64-col B slice direct from L2 with a rotating 3-slot register pipeline
// (prefetch distance 2 tiles ~ covers loaded-L2 latency). Barrier-free
// K-loop, A register-dbuf from LDS. mfma_i32_16x16x64_i8 exact. 3 blocks/CU.
// Fused exp2 + row/col sums + diag.
__global__ __launch_bounds__(256, 3) void infonce_main(const uint8_t* __restrict__ P,
                                                       const uint8_t* __restrict__ T,
                                                       float* __restrict__ row_sum,
                                                       float* __restrict__ col_sum,
                                                       float* __restrict__ diag) {
  __shared__ __align__(16) uint8_t Asm[32768];  // 64 rows x 512 k

  // XCD raster: xcd owns 32 brow strips (2048 rows = 1 MB i8, L2-resident);
  // within XCD, brow fastest -> concurrent blocks share the bcol B-tile.
  int bid = blockIdx.x;          // 0..16383
  int xcd = bid & 7;
  int q = bid >> 3;              // 0..2047
  int brow = (xcd * 32 + (q & 31)) << 6;
  int bcol = (q >> 5) << 8;      // 256-col tiles

  int tid = threadIdx.x;
  int lane = tid & 63;
  int wid = tid >> 6;
  int wc = wid * 64;             // wave's 64-col slice
  int rlane = lane >> 4;
  int clane = lane & 15;

  // Stage A-panel: one contiguous 32-KB linear copy (8 x gload_lds/thread).
  size_t abase = (size_t)(brow >> 6) * 32768;
#pragma unroll
  for (int it = 0; it < 8; ++it) {
    int s = it * 256 + tid;
    __builtin_amdgcn_global_load_lds((gptr_t)(P + abase + (size_t)s * 16),
                                     (lptr_t)(&Asm[0] + (size_t)s * 16), 16, 0, 0);
  }
  __syncthreads();  // the ONLY barrier: A-panel resident

  const uint8_t* lA = &Asm[(size_t)lane * 16];
  const uint8_t* pB = T + (size_t)((bcol + wc) >> 6) * 32768 + (size_t)lane * 16;

  i32x4 acc[4][4] = {};

  // Depth-2 B pipeline: 3 rotating slots (all indices compile-time after
  // full unroll). A: register dbuf from LDS (r14-proven).
  i32x4 b[3][4], a[4], an[4];
#pragma unroll
  for (int n = 0; n < 4; ++n) b[0][n] = *(const i32x4*)(pB + 0 * 4096 + n * 1024);
#pragma unroll
  for (int n = 0; n < 4; ++n) b[1][n] = *(const i32x4*)(pB + 1 * 4096 + n * 1024);
#pragma unroll
  for (int m = 0; m < 4; ++m) a[m] = *(const i32x4*)(lA + m * 1024);

#pragma unroll
  for (int t = 0; t < 8; ++t) {
    if (t < 6) {
#pragma unroll
      for (int n = 0; n < 4; ++n)
        b[(t + 2) % 3][n] = *(const i32x4*)(pB + (t + 2) * 4096 + n * 1024);
    }
    if (t < 7) {
#pragma unroll
      for (int m = 0; m < 4; ++m)
        an[m] = *(const i32x4*)(lA + (t + 1) * 4096 + m * 1024);
    }
#pragma unroll
    for (int m = 0; m < 4; ++m)
#pragma unroll
      for (int n = 0; n < 4; ++n)
        acc[m][n] = __builtin_amdgcn_mfma_i32_16x16x64_i8(a[m], b[t % 3][n], acc[m][n], 0, 0, 0);
    if (t < 7) {
#pragma unroll
      for (int m = 0; m < 4; ++m) a[m] = an[m];
    }
  }

  // Epilogue: ex = 2^(acc * S*log2e); diag only in its branch.
  f32x4 ex[4][4];
#pragma unroll
  for (int m = 0; m < 4; ++m)
#pragma unroll
    for (int n = 0; n < 4; ++n)
#pragma unroll
      for (int j = 0; j < 4; ++j) {
        float ai = (float)acc[m][n][j];
        int grow = brow + m * 16 + rlane * 4 + j;
        int gcol = bcol + wc + n * 16 + clane;
        if (grow == gcol) diag[grow] = ai * ILOGIT_SCALE;
        ex[m][n][j] = exp2f(ai * ILOGIT_SCALE_L2);
      }

  // Row sums: reduce over n-fragments then across the 16-lane column group.
#pragma unroll
  for (int m = 0; m < 4; ++m)
#pragma unroll
    for (int j = 0; j < 4; ++j) {
      float rs = ex[m][0][j] + ex[m][1][j] + ex[m][2][j] + ex[m][3][j];
      rs += __shfl_xor(rs, 1);
      rs += __shfl_xor(rs, 2);
      rs += __shfl_xor(rs, 4);
      rs += __shfl_xor(rs, 8);
      if (clane == 0) atomicAdd(&row_sum[brow + m * 16 + rlane * 4 + j], rs);
    }

  // Col sums: reduce over m-fragments and regs, then across the 4 row groups.
#pragma unroll
  for (int n = 0; n < 4; ++n) {
    float cs = 0.f;
#pragma unroll
    for (int m = 0; m < 4; ++m)
#pragma unroll
      for (int j = 0; j < 4; ++j) cs += ex[m][n][j];
    cs += __shfl_xor(cs, 16);
    cs += __shfl_xor(cs, 32);
    if (rlane == 0) atomicAdd(&col_sum[bcol + wc + n * 16 + clane], cs);
  }
}

__global__ __launch_bounds__(256) void finalize_kernel(const float* __restrict__ rs,
                                                       const float* __restrict__ cs,
                                                       const float* __restrict__ dg,
                                                       float* __restrict__ out) {
  float s = 0.f;
  for (int i = threadIdx.x; i < B_DIM; i += 256)
    s += 0.5f * (logf(rs[i]) + logf(cs[i])) - dg[i];
#pragma unroll
  for (int m = 1; m < 64; m <<= 1) s += __shfl_xor(s, m);
  __shared__ float red[4];
  if ((threadIdx.x & 63) == 0) red[threadIdx.x >> 6] = s;
  __syncthreads();
  if (threadIdx.x == 0)
    out[0] = (red[0] + red[1] + red[2] + red[3]) * (1.0f / (float)B_DIM);
}

extern "C" void kernel_launch(void* const* d_in, const int* in_sizes, int n_in,
                              void* d_out, int out_size, void* d_ws, size_t ws_size,
                              hipStream_t stream) {
  const float* p = (const float*)d_in[0];
  const float* t = (const float*)d_in[1];
  float* out = (float*)d_out;

  char* ws = (char*)d_ws;
  const size_t embBytes = (size_t)B_DIM * D_DIM;  // 8 MB i8
  uint8_t* Pn = (uint8_t*)ws;
  uint8_t* Tn = (uint8_t*)(ws + embBytes);
  float* row_sum = (float*)(ws + 2 * embBytes);
  float* col_sum = row_sum + B_DIM;
  float* diag = col_sum + B_DIM;

  hipMemsetAsync(row_sum, 0, 2 * (size_t)B_DIM * sizeof(float), stream);
  normalize_kernel<<<B_DIM / 4, 256, 0, stream>>>(p, Pn);
  normalize_kernel<<<B_DIM / 4, 256, 0, stream>>>(t, Tn);
  infonce_main<<<(B_DIM / 64) * (B_DIM / 256), 256, 0, stream>>>(Pn, Tn, row_sum, col_sum, diag);
  finalize_kernel<<<1, 256, 0, stream>>>(row_sum, col_sum, diag, out);
}

// Round 19
// 242.078 us; speedup vs baseline: 2.0840x; 1.0110x over previous
//
#include <hip/hip_runtime.h>
#include <hip/hip_bf16.h>
#include <stdint.h>

#define B_DIM 16384
#define D_DIM 512
// Embeddings quantized as int8 q = rne(127*x): dot scales by 127^2.
#define ILOGIT_SCALE (1.0f / (127.0f * 127.0f * 0.07f))
#define ILOGIT_SCALE_L2 (ILOGIT_SCALE * 1.44269504088896340736f)

typedef int i32x4 __attribute__((ext_vector_type(4)));
typedef float f32x4 __attribute__((ext_vector_type(4)));

typedef const __attribute__((address_space(1))) void* gptr_t;
typedef __attribute__((address_space(3))) void* lptr_t;

// Fragment-linear i8 layout, 64-ROW chunks (identical for Pn and Tn):
//   chunk(RB = row>>6, KT = k>>6) = (RB*8 + KT)*4096 bytes   (64 rows x 64 k)
//   subtile mq = (row>>4)&3 -> 1 KB at mq*1024
//   slot lane = ((k>>4)&3)*16 + (row&15) -> 16 B at lane*16
//   byte = k&15
// => one i8 MFMA fragment = ONE contiguous 1-KB lane-linear read, and a
//    64-row panel (all K) = ONE contiguous 32-KB span.

// One wave per row: load 512 fp32, L2-normalize, quantize q=rne(127x),
// write one 8-B fragment slot per lane. (r12-proven.)
__global__ __launch_bounds__(256) void normalize_kernel(const float* __restrict__ in,
                                                        uint8_t* __restrict__ out) {
  int wid = threadIdx.x >> 6;
  int lane = threadIdx.x & 63;
  int row = blockIdx.x * 4 + wid;
  const float* r = in + (size_t)row * D_DIM;
  float4 v0 = ((const float4*)r)[lane * 2];
  float4 v1 = ((const float4*)r)[lane * 2 + 1];
  float ssq = v0.x * v0.x + v0.y * v0.y + v0.z * v0.z + v0.w * v0.w +
              v1.x * v1.x + v1.y * v1.y + v1.z * v1.z + v1.w * v1.w;
#pragma unroll
  for (int m = 1; m < 64; m <<= 1) ssq += __shfl_xor(ssq, m);
  float s = 127.0f / fmaxf(sqrtf(ssq), 1e-12f);
  int q0 = __float2int_rn(v0.x * s), q1 = __float2int_rn(v0.y * s);
  int q2 = __float2int_rn(v0.z * s), q3 = __float2int_rn(v0.w * s);
  int q4 = __float2int_rn(v1.x * s), q5 = __float2int_rn(v1.y * s);
  int q6 = __float2int_rn(v1.z * s), q7 = __float2int_rn(v1.w * s);
  uint2 o;
  o.x = (uint32_t)(q0 & 255) | ((uint32_t)(q1 & 255) << 8) |
        ((uint32_t)(q2 & 255) << 16) | ((uint32_t)q3 << 24);
  o.y = (uint32_t)(q4 & 255) | ((uint32_t)(q5 & 255) << 8) |
        ((uint32_t)(q6 & 255) << 16) | ((uint32_t)q7 << 24);
  size_t addr = ((size_t)(row >> 6) * 8 + (lane >> 3)) * 4096 +
                (size_t)((row >> 4) & 3) * 1024 +
                (size_t)((((lane >> 1) & 3) << 4) | (row & 15)) * 16 +
                (lane & 1) * 8;
  *(uint2*)(out + addr) = o;
}

// i8 64x256-tile NT GEMM (r16 light body + 5 blocks/CU): 4 waves share a
// 64-row A-panel in 32 KB LDS (one barrier); each wave owns a 64-col B
// slice direct from L2, depth-1 register prefetch; A read JIT from LDS.
// __launch_bounds__(256,5): 5 blocks/CU (160 KB LDS), VGPR cap 102 —
// light body fits (r16 compiled at 64). Diag hoisted behind a block-
// uniform branch; raw v_exp_f32 for exp2. Fused epilogue.
__global__ __launch_bounds__(256, 5) void infonce_main(const uint8_t* __restrict__ P,
                                                       const uint8_t* __restrict__ T,
                                                       float* __restrict__ row_sum,
                                                       float* __restrict__ col_sum,
                                                       float* __restrict__ diag) {
  __shared__ __align__(16) uint8_t Asm[32768];  // 64 rows x 512 k

  // XCD raster: xcd owns 32 brow strips (2048 rows = 1 MB i8, L2-resident);
  // within XCD, brow fastest -> concurrent blocks share the bcol B-tile.
  int bid = blockIdx.x;          // 0..16383
  int xcd = bid & 7;
  int q = bid >> 3;              // 0..2047
  int brow = (xcd * 32 + (q & 31)) << 6;
  int bcol = (q >> 5) << 8;      // 256-col tiles

  int tid = threadIdx.x;
  int lane = tid & 63;
  int wid = tid >> 6;
  int wc = wid * 64;             // wave's 64-col slice
  int rlane = lane >> 4;
  int clane = lane & 15;

  // Stage A-panel: one contiguous 32-KB linear copy (8 x gload_lds/thread).
  size_t abase = (size_t)(brow >> 6) * 32768;
#pragma unroll
  for (int it = 0; it < 8; ++it) {
    int s = it * 256 + tid;
    __builtin_amdgcn_global_load_lds((gptr_t)(P + abase + (size_t)s * 16),
                                     (lptr_t)(&Asm[0] + (size_t)s * 16), 16, 0, 0);
  }
  __syncthreads();  // the ONLY barrier: A-panel resident

  const uint8_t* lA = &Asm[(size_t)lane * 16];
  const uint8_t* pB = T + (size_t)((bcol + wc) >> 6) * 32768 + (size_t)lane * 16;

  i32x4 acc[4][4] = {};

  i32x4 b[4];
#pragma unroll
  for (int n = 0; n < 4; ++n) b[n] = *(const i32x4*)(pB + n * 1024);

#pragma unroll
  for (int t = 0; t < 8; ++t) {
    i32x4 bn[4];
    if (t < 7) {
#pragma unroll
      for (int n = 0; n < 4; ++n)
        bn[n] = *(const i32x4*)(pB + (t + 1) * 4096 + n * 1024);
    }
    i32x4 a[4];
#pragma unroll
    for (int m = 0; m < 4; ++m)
      a[m] = *(const i32x4*)(lA + t * 4096 + m * 1024);
#pragma unroll
    for (int m = 0; m < 4; ++m)
#pragma unroll
      for (int n = 0; n < 4; ++n)
        acc[m][n] = __builtin_amdgcn_mfma_i32_16x16x64_i8(a[m], b[n], acc[m][n], 0, 0, 0);
    if (t < 7) {
#pragma unroll
      for (int n = 0; n < 4; ++n) b[n] = bn[n];
    }
  }

  // Diagonal capture, hoisted: only blocks whose row/col ranges intersect
  // ([brow,brow+64) x [bcol,bcol+256)) contain diagonal elements — 1/64.
  if (brow < bcol + 256 && bcol < brow + 64) {
#pragma unroll
    for (int m = 0; m < 4; ++m)
#pragma unroll
      for (int n = 0; n < 4; ++n)
#pragma unroll
        for (int j = 0; j < 4; ++j) {
          int grow = brow + m * 16 + rlane * 4 + j;
          int gcol = bcol + wc + n * 16 + clane;
          if (grow == gcol) diag[grow] = (float)acc[m][n][j] * ILOGIT_SCALE;
        }
  }

  // Epilogue: ex = 2^(acc * S*log2e) via raw v_exp_f32 (args bounded ±21).
  f32x4 ex[4][4];
#pragma unroll
  for (int m = 0; m < 4; ++m)
#pragma unroll
    for (int n = 0; n < 4; ++n)
#pragma unroll
      for (int j = 0; j < 4; ++j)
        ex[m][n][j] = __builtin_amdgcn_exp2f((float)acc[m][n][j] * ILOGIT_SCALE_L2);

  // Row sums: reduce over n-fragments then across the 16-lane column group.
#pragma unroll
  for (int m = 0; m < 4; ++m)
#pragma unroll
    for (int j = 0; j < 4; ++j) {
      float rs = ex[m][0][j] + ex[m][1][j] + ex[m][2][j] + ex[m][3][j];
      rs += __shfl_xor(rs, 1);
      rs += __shfl_xor(rs, 2);
      rs += __shfl_xor(rs, 4);
      rs += __shfl_xor(rs, 8);
      if (clane == 0) atomicAdd(&row_sum[brow + m * 16 + rlane * 4 + j], rs);
    }

  // Col sums: reduce over m-fragments and regs, then across the 4 row groups.
#pragma unroll
  for (int n = 0; n < 4; ++n) {
    float cs = 0.f;
#pragma unroll
    for (int m = 0; m < 4; ++m)
#pragma unroll
      for (int j = 0; j < 4; ++j) cs += ex[m][n][j];
    cs += __shfl_xor(cs, 16);
    cs += __shfl_xor(cs, 32);
    if (rlane == 0) atomicAdd(&col_sum[bcol + wc + n * 16 + clane], cs);
  }
}

__global__ __launch_bounds__(256) void finalize_kernel(const float* __restrict__ rs,
                                                       const float* __restrict__ cs,
                                                       const float* __restrict__ dg,
                                                       float* __restrict__ out) {
  float s = 0.f;
  for (int i = threadIdx.x; i < B_DIM; i += 256)
    s += 0.5f * (logf(rs[i]) + logf(cs[i])) - dg[i];
#pragma unroll
  for (int m = 1; m < 64; m <<= 1) s += __shfl_xor(s, m);
  __shared__ float red[4];
  if ((threadIdx.x & 63) == 0) red[threadIdx.x >> 6] = s;
  __syncthreads();
  if (threadIdx.x == 0)
    out[0] = (red[0] + red[1] + red[2] + red[3]) * (1.0f / (float)B_DIM);
}

extern "C" void kernel_launch(void* const* d_in, const int* in_sizes, int n_in,
                              void* d_out, int out_size, void* d_ws, size_t ws_size,
                              hipStream_t stream) {
  const float* p = (const float*)d_in[0];
  const float* t = (const float*)d_in[1];
  float* out = (float*)d_out;

  char* ws = (char*)d_ws;
  const size_t embBytes = (size_t)B_DIM * D_DIM;  // 8 MB i8
  uint8_t* Pn = (uint8_t*)ws;
  uint8_t* Tn = (uint8_t*)(ws + embBytes);
  float* row_sum = (float*)(ws + 2 * embBytes);
  float* col_sum = row_sum + B_DIM;
  float* diag = col_sum + B_DIM;

  hipMemsetAsync(row_sum, 0, 2 * (size_t)B_DIM * sizeof(float), stream);
  normalize_kernel<<<B_DIM / 4, 256, 0, stream>>>(p, Pn);
  normalize_kernel<<<B_DIM / 4, 256, 0, stream>>>(t, Tn);
  infonce_main<<<(B_DIM / 64) * (B_DIM / 256), 256, 0, stream>>>(Pn, Tn, row_sum, col_sum, diag);
  finalize_kernel<<<1, 256, 0, stream>>>(row_sum, col_sum, diag, out);
}

// Round 20
// 224.990 us; speedup vs baseline: 2.2423x; 1.0760x over previous
//
#include <hip/hip_runtime.h>
#include <hip/hip_bf16.h>
#include <stdint.h>

#define B_DIM 16384
#define D_DIM 512
// Embeddings quantized as int8 q = rne(127*x): dot scales by 127^2.
#define ILOGIT_SCALE (1.0f / (127.0f * 127.0f * 0.07f))
#define ILOGIT_SCALE_L2 (ILOGIT_SCALE * 1.44269504088896340736f)

typedef int i32x4 __attribute__((ext_vector_type(4)));
typedef float f32x4 __attribute__((ext_vector_type(4)));

typedef const __attribute__((address_space(1))) void* gptr_t;
typedef __attribute__((address_space(3))) void* lptr_t;

// Fragment-linear i8 layout, 64-ROW chunks (identical for Pn and Tn):
//   chunk(RB = row>>6, KT = k>>6) = (RB*8 + KT)*4096 bytes   (64 rows x 64 k)
//   subtile mq = (row>>4)&3 -> 1 KB at mq*1024
//   slot lane = ((k>>4)&3)*16 + (row&15) -> 16 B at lane*16
//   byte = k&15
// => one i8 MFMA fragment = ONE contiguous 1-KB lane-linear read, and a
//    64-row panel (all K) = ONE contiguous 32-KB span.

// Fused normalize for BOTH tensors: blocks [0,4096) -> P, [4096,8192) -> T.
// One wave per row: load 512 fp32, L2-normalize, quantize q=rne(127x),
// write one 8-B fragment slot per lane. (r12-proven body.)
__global__ __launch_bounds__(256) void normalize_kernel(const float* __restrict__ pin,
                                                        const float* __restrict__ tin,
                                                        uint8_t* __restrict__ pout,
                                                        uint8_t* __restrict__ tout) {
  int half = blockIdx.x >> 12;  // 0: P, 1: T
  int blk = blockIdx.x & 4095;
  const float* in = half ? tin : pin;
  uint8_t* out = half ? tout : pout;
  int wid = threadIdx.x >> 6;
  int lane = threadIdx.x & 63;
  int row = blk * 4 + wid;
  const float* r = in + (size_t)row * D_DIM;
  float4 v0 = ((const float4*)r)[lane * 2];
  float4 v1 = ((const float4*)r)[lane * 2 + 1];
  float ssq = v0.x * v0.x + v0.y * v0.y + v0.z * v0.z + v0.w * v0.w +
              v1.x * v1.x + v1.y * v1.y + v1.z * v1.z + v1.w * v1.w;
#pragma unroll
  for (int m = 1; m < 64; m <<= 1) ssq += __shfl_xor(ssq, m);
  float s = 127.0f / fmaxf(sqrtf(ssq), 1e-12f);
  int q0 = __float2int_rn(v0.x * s), q1 = __float2int_rn(v0.y * s);
  int q2 = __float2int_rn(v0.z * s), q3 = __float2int_rn(v0.w * s);
  int q4 = __float2int_rn(v1.x * s), q5 = __float2int_rn(v1.y * s);
  int q6 = __float2int_rn(v1.z * s), q7 = __float2int_rn(v1.w * s);
  uint2 o;
  o.x = (uint32_t)(q0 & 255) | ((uint32_t)(q1 & 255) << 8) |
        ((uint32_t)(q2 & 255) << 16) | ((uint32_t)q3 << 24);
  o.y = (uint32_t)(q4 & 255) | ((uint32_t)(q5 & 255) << 8) |
        ((uint32_t)(q6 & 255) << 16) | ((uint32_t)q7 << 24);
  size_t addr = ((size_t)(row >> 6) * 8 + (lane >> 3)) * 4096 +
                (size_t)((row >> 4) & 3) * 1024 +
                (size_t)((((lane >> 1) & 3) << 4) | (row & 15)) * 16 +
                (lane & 1) * 8;
  *(uint2*)(out + addr) = o;
}

// i8 64x256-tile NT GEMM (champion structure, issue-slot-trimmed):
// 4 waves share a 64-row A-panel in 32 KB LDS (one barrier); each wave owns
// a 64-col B slice direct from L2. K-loop unrolled x2 with alternating
// b0/b1 register sets: depth-1 prefetch, ZERO rotation movs. A read JIT
// from LDS (lane-linear, conflict-free). Diag hoisted behind block-uniform
// branch; raw v_exp_f32. mfma_i32_16x16x64_i8 exact. ~4 blocks/CU.
__global__ __launch_bounds__(256, 4) void infonce_main(const uint8_t* __restrict__ P,
                                                       const uint8_t* __restrict__ T,
                                                       float* __restrict__ row_sum,
                                                       float* __restrict__ col_sum,
                                                       float* __restrict__ diag) {
  __shared__ __align__(16) uint8_t Asm[32768];  // 64 rows x 512 k

  // XCD raster: xcd owns 32 brow strips (2048 rows = 1 MB i8, L2-resident);
  // within XCD, brow fastest -> concurrent blocks share the bcol B-tile.
  int bid = blockIdx.x;          // 0..16383
  int xcd = bid & 7;
  int q = bid >> 3;              // 0..2047
  int brow = (xcd * 32 + (q & 31)) << 6;
  int bcol = (q >> 5) << 8;      // 256-col tiles

  int tid = threadIdx.x;
  int lane = tid & 63;
  int wid = tid >> 6;
  int wc = wid * 64;             // wave's 64-col slice
  int rlane = lane >> 4;
  int clane = lane & 15;

  // Stage A-panel: one contiguous 32-KB linear copy (8 x gload_lds/thread).
  size_t abase = (size_t)(brow >> 6) * 32768;
#pragma unroll
  for (int it = 0; it < 8; ++it) {
    int s = it * 256 + tid;
    __builtin_amdgcn_global_load_lds((gptr_t)(P + abase + (size_t)s * 16),
                                     (lptr_t)(&Asm[0] + (size_t)s * 16), 16, 0, 0);
  }
  __syncthreads();  // the ONLY barrier: A-panel resident

  const uint8_t* lA = &Asm[(size_t)lane * 16];
  const uint8_t* pB = T + (size_t)((bcol + wc) >> 6) * 32768 + (size_t)lane * 16;

  i32x4 acc[4][4] = {};

#define LDB(dst, t)                                                            \
  _Pragma("unroll") for (int n = 0; n < 4; ++n)                                \
      dst[n] = *(const i32x4*)(pB + (t) * 4096 + n * 1024)
#define LDA(dst, t)                                                            \
  _Pragma("unroll") for (int m = 0; m < 4; ++m)                                \
      dst[m] = *(const i32x4*)(lA + (t) * 4096 + m * 1024)
#define MM(aa, bb)                                                             \
  _Pragma("unroll") for (int m = 0; m < 4; ++m)                                \
      _Pragma("unroll") for (int n = 0; n < 4; ++n)                            \
          acc[m][n] = __builtin_amdgcn_mfma_i32_16x16x64_i8(aa[m], bb[n], acc[m][n], 0, 0, 0)

  i32x4 b0[4], b1[4], a[4];
  LDB(b0, 0);
#pragma unroll
  for (int tt = 0; tt < 4; ++tt) {
    const int t = tt * 2;
    if (t + 1 <= 7) LDB(b1, t + 1);   // prefetch t+1, covered by MM(t)
    LDA(a, t);
    MM(a, b0);
    if (t + 2 <= 7) LDB(b0, t + 2);   // prefetch t+2, covered by MM(t+1)
    LDA(a, t + 1);
    MM(a, b1);
  }
#undef LDB
#undef LDA
#undef MM

  // Diagonal capture, hoisted: only 1/64 blocks intersect the diagonal.
  if (brow < bcol + 256 && bcol < brow + 64) {
#pragma unroll
    for (int m = 0; m < 4; ++m)
#pragma unroll
      for (int n = 0; n < 4; ++n)
#pragma unroll
        for (int j = 0; j < 4; ++j) {
          int grow = brow + m * 16 + rlane * 4 + j;
          int gcol = bcol + wc + n * 16 + clane;
          if (grow == gcol) diag[grow] = (float)acc[m][n][j] * ILOGIT_SCALE;
        }
  }

  // Epilogue: ex = 2^(acc * S*log2e) via raw v_exp_f32 (args bounded ±21).
  f32x4 ex[4][4];
#pragma unroll
  for (int m = 0; m < 4; ++m)
#pragma unroll
    for (int n = 0; n < 4; ++n)
#pragma unroll
      for (int j = 0; j < 4; ++j)
        ex[m][n][j] = __builtin_amdgcn_exp2f((float)acc[m][n][j] * ILOGIT_SCALE_L2);

  // Row sums: reduce over n-fragments then across the 16-lane column group.
#pragma unroll
  for (int m = 0; m < 4; ++m)
#pragma unroll
    for (int j = 0; j < 4; ++j) {
      float rs = ex[m][0][j] + ex[m][1][j] + ex[m][2][j] + ex[m][3][j];
      rs += __shfl_xor(rs, 1);
      rs += __shfl_xor(rs, 2);
      rs += __shfl_xor(rs, 4);
      rs += __shfl_xor(rs, 8);
      if (clane == 0) atomicAdd(&row_sum[brow + m * 16 + rlane * 4 + j], rs);
    }

  // Col sums: reduce over m-fragments and regs, then across the 4 row groups.
#pragma unroll
  for (int n = 0; n < 4; ++n) {
    float cs = 0.f;
#pragma unroll
    for (int m = 0; m < 4; ++m)
#pragma unroll
      for (int j = 0; j < 4; ++j) cs += ex[m][n][j];
    cs += __shfl_xor(cs, 16);
    cs += __shfl_xor(cs, 32);
    if (rlane == 0) atomicAdd(&col_sum[bcol + wc + n * 16 + clane], cs);
  }
}

__global__ __launch_bounds__(256) void finalize_kernel(const float* __restrict__ rs,
                                                       const float* __restrict__ cs,
                                                       const float* __restrict__ dg,
                                                       float* __restrict__ out) {
  float s = 0.f;
  for (int i = threadIdx.x; i < B_DIM; i += 256)
    s += 0.5f * (logf(rs[i]) + logf(cs[i])) - dg[i];
#pragma unroll
  for (int m = 1; m < 64; m <<= 1) s += __shfl_xor(s, m);
  __shared__ float red[4];
  if ((threadIdx.x & 63) == 0) red[threadIdx.x >> 6] = s;
  __syncthreads();
  if (threadIdx.x == 0)
    out[0] = (red[0] + red[1] + red[2] + red[3]) * (1.0f / (float)B_DIM);
}

extern "C" void kernel_launch(void* const* d_in, const int* in_sizes, int n_in,
                              void* d_out, int out_size, void* d_ws, size_t ws_size,
                              hipStream_t stream) {
  const float* p = (const float*)d_in[0];
  const float* t = (const float*)d_in[1];
  float* out = (float*)d_out;

  char* ws = (char*)d_ws;
  const size_t embBytes = (size_t)B_DIM * D_DIM;  // 8 MB i8
  uint8_t* Pn = (uint8_t*)ws;
  uint8_t* Tn = (uint8_t*)(ws + embBytes);
  float* row_sum = (float*)(ws + 2 * embBytes);
  float* col_sum = row_sum + B_DIM;
  float* diag = col_sum + B_DIM;

  hipMemsetAsync(row_sum, 0, 2 * (size_t)B_DIM * sizeof(float), stream);
  normalize_kernel<<<B_DIM / 2, 256, 0, stream>>>(p, t, Pn, Tn);
  infonce_main<<<(B_DIM / 64) * (B_DIM / 256), 256, 0, stream>>>(Pn, Tn, row_sum, col_sum, diag);
  finalize_kernel<<<1, 256, 0, stream>>>(row_sum, col_sum, diag, out);
}